// Round 7
// baseline (388.953 us; speedup 1.0000x reference)
//
#include <hip/hip_runtime.h>
#include <math.h>

#define N4C 32768
#define N3C 65536
#define N2C 131072
#define N1C 262144

typedef _Float16 f16x8 __attribute__((ext_vector_type(8)));
typedef _Float16 f16x4 __attribute__((ext_vector_type(4)));
typedef float f32x4 __attribute__((ext_vector_type(4)));

__device__ __forceinline__ f32x4 mfma16(f16x8 a, f16x8 b, f32x4 c) {
  return __builtin_amdgcn_mfma_f32_16x16x32_f16(a, b, c, 0, 0, 0);
}

// fast celu: expm1(x) ~= __expf(x)-1 (v_exp_f32, abs err ~1e-7)
__device__ __forceinline__ float celuf(float x) {
  return x > 0.f ? x : (__expf(x) - 1.f);
}

// log_sigmoid(x) = min(x,0) - log(1 + exp(-|x|))
__device__ __forceinline__ float logsigf(float x) {
  float e = __expf(-fabsf(x));
  return fminf(x, 0.f) - __logf(1.f + e);
}

// ---------------------------------------------------------------------------
// Prep: z_mask [N4*64] f32 -> zf f16 (4 MB table for l3 gathers)
// ---------------------------------------------------------------------------
__global__ __launch_bounds__(256) void zhalf_kernel(const float* __restrict__ z,
                                                    _Float16* __restrict__ zf) {
  const int i = (blockIdx.x * 256 + threadIdx.x) * 4;
  float4 f = *(const float4*)(z + i);
  f16x4 h;
  h[0] = (_Float16)f.x; h[1] = (_Float16)f.y;
  h[2] = (_Float16)f.z; h[3] = (_Float16)f.w;
  __builtin_nontemporal_store(h, (f16x4*)(zf + i));
}

// ---------------------------------------------------------------------------
// Level 3: PointConv (64 -> 64 -> 32), f16 MFMA, wave per point (16 edges = M).
// Round-4 structure (best known: simple dynamic loop, max occupancy).
// Changes: nt hints on streams, f16 LDS round trip (no cvt on read side).
// ---------------------------------------------------------------------------
__global__ __launch_bounds__(256) void l3_kernel(
    const _Float16* __restrict__ zf, const float* __restrict__ pos4,
    const float* __restrict__ pos3, const int* __restrict__ src3,
    const float* __restrict__ w1a, const float* __restrict__ b1a,
    const float* __restrict__ w1b, const float* __restrict__ b1b,
    _Float16* __restrict__ x3f) {
  __shared__ _Float16 hbuf[4][16 * 80];  // [16 rows][80 halfs], 160 B rows: 16B-aligned
  const int lane = threadIdx.x & 63;
  const int wid = threadIdx.x >> 6;
  const int col = lane & 15;   // MFMA n / A row m (edge)
  const int quad = lane >> 4;  // k-subchunk selector
  _Float16* hw = hbuf[wid];

  // B frags layer a: B[k][n], k = c*32 + quad*8 + j (K=67 pad 96), n = t*16+col
  f16x8 Ba[3][4];
#pragma unroll
  for (int c = 0; c < 3; ++c)
#pragma unroll
    for (int t = 0; t < 4; ++t)
#pragma unroll
      for (int j = 0; j < 8; ++j) {
        int k = c * 32 + quad * 8 + j;
        Ba[c][t][j] = (k < 67) ? (_Float16)w1a[k * 64 + t * 16 + col] : (_Float16)0.f;
      }
  f16x8 Bb[2][2];
#pragma unroll
  for (int c = 0; c < 2; ++c)
#pragma unroll
    for (int t = 0; t < 2; ++t)
#pragma unroll
      for (int j = 0; j < 8; ++j) {
        int k = c * 32 + quad * 8 + j;
        Bb[c][t][j] = (_Float16)w1b[k * 32 + t * 16 + col];
      }
  const float biasA0 = b1a[col], biasA1 = b1a[16 + col];
  const float biasA2 = b1a[32 + col], biasA3 = b1a[48 + col];
  const float biasB0 = b1b[col], biasB1 = b1b[16 + col];

  const int gwave = blockIdx.x * 4 + wid;
  const int nw = gridDim.x * 4;

  f16x8 A2 = {};  // only quad0 j0..2 rewritten per point; rest stay 0

  for (int p = gwave; p < N3C; p += nw) {
    const int s = __builtin_nontemporal_load(src3 + p * 16 + col);
    const float po0 = __builtin_nontemporal_load(pos3 + p * 3);
    const float po1 = __builtin_nontemporal_load(pos3 + p * 3 + 1);
    const float po2 = __builtin_nontemporal_load(pos3 + p * 3 + 2);

    const _Float16* zr = zf + (size_t)s * 64;
    f16x8 A0 = *(const f16x8*)(zr + quad * 8);        // k 0..31
    f16x8 A1 = *(const f16x8*)(zr + 32 + quad * 8);   // k 32..63
    if (quad == 0) {                                  // k 64..66 = rel
      A2[0] = (_Float16)(pos4[s * 3 + 0] - po0);
      A2[1] = (_Float16)(pos4[s * 3 + 1] - po1);
      A2[2] = (_Float16)(pos4[s * 3 + 2] - po2);
    }

    f32x4 d[4];
#pragma unroll
    for (int t = 0; t < 4; ++t) {
      f32x4 acc = {0.f, 0.f, 0.f, 0.f};
      acc = mfma16(A0, Ba[0][t], acc);
      acc = mfma16(A1, Ba[1][t], acc);
      acc = mfma16(A2, Ba[2][t], acc);
      d[t] = acc;
    }
    // C layout: row = quad*4 + r, col = n. celu -> f16 LDS [16][80].
#pragma unroll
    for (int r = 0; r < 4; ++r) {
      _Float16* bp = hw + (quad * 4 + r) * 80 + col;
      bp[0]  = (_Float16)celuf(d[0][r] + biasA0);
      bp[16] = (_Float16)celuf(d[1][r] + biasA1);
      bp[32] = (_Float16)celuf(d[2][r] + biasA2);
      bp[48] = (_Float16)celuf(d[3][r] + biasA3);
    }
    // same-wave LDS, in-order: no barrier. A'[m=col][k=c*32+quad*8+j]
    // f16 rows: one ds_read_b128 per chunk, zero conversions.
    f16x8 P0 = *(const f16x8*)(hw + col * 80 + quad * 8);
    f16x8 P1 = *(const f16x8*)(hw + col * 80 + 32 + quad * 8);
    f32x4 e[2];
#pragma unroll
    for (int t = 0; t < 2; ++t) {
      f32x4 acc = {0.f, 0.f, 0.f, 0.f};
      acc = mfma16(P0, Bb[0][t], acc);
      acc = mfma16(P1, Bb[1][t], acc);
      e[t] = acc;
    }
    float m0 = fmaxf(fmaxf(e[0][0], e[0][1]), fmaxf(e[0][2], e[0][3]));
    float m1 = fmaxf(fmaxf(e[1][0], e[1][1]), fmaxf(e[1][2], e[1][3]));
    m0 = fmaxf(m0, __shfl_xor(m0, 16, 64));
    m0 = fmaxf(m0, __shfl_xor(m0, 32, 64));
    m1 = fmaxf(m1, __shfl_xor(m1, 16, 64));
    m1 = fmaxf(m1, __shfl_xor(m1, 32, 64));
    if (lane < 16) {
      _Float16* row = x3f + (size_t)p * 32;
      __builtin_nontemporal_store((_Float16)celuf(m0 + biasB0), row + col);
      __builtin_nontemporal_store((_Float16)celuf(m1 + biasB1), row + 16 + col);
    }
  }
}

// ---------------------------------------------------------------------------
// Level 2: PointConv (32 -> 16 -> 16), f16 MFMA wave-per-point (round-4 loop).
// ---------------------------------------------------------------------------
__global__ __launch_bounds__(256) void l2_kernel(
    const _Float16* __restrict__ x3f, const float* __restrict__ pos3,
    const float* __restrict__ pos2, const int* __restrict__ src2,
    const float* __restrict__ w2a, const float* __restrict__ b2a,
    const float* __restrict__ w2b, const float* __restrict__ b2b,
    _Float16* __restrict__ x2f) {
  __shared__ _Float16 hbuf[4][16 * 24];  // 48 B rows: 16B-aligned
  const int lane = threadIdx.x & 63;
  const int wid = threadIdx.x >> 6;
  const int col = lane & 15;
  const int quad = lane >> 4;
  _Float16* hw = hbuf[wid];

  f16x8 Ba0, Ba1, Bb;
#pragma unroll
  for (int j = 0; j < 8; ++j) {
    int k = quad * 8 + j;
    Ba0[j] = (_Float16)w2a[k * 16 + col];                       // k 0..31
    Ba1[j] = (k + 32 < 35) ? (_Float16)w2a[(k + 32) * 16 + col] // k 32..34
                           : (_Float16)0.f;
    Bb[j] = (k < 16) ? (_Float16)w2b[k * 16 + col] : (_Float16)0.f;
  }
  const float biasA = b2a[col];
  const float biasB = b2b[col];

  const int gwave = blockIdx.x * 4 + wid;
  const int nw = gridDim.x * 4;

  f16x8 A1 = {};  // quad0 j0..2 rewritten per point
  f16x8 P = {};   // quads 0,1 fully rewritten per point

  for (int p = gwave; p < N2C; p += nw) {
    const int s = __builtin_nontemporal_load(src2 + p * 16 + col);
    const float po0 = __builtin_nontemporal_load(pos2 + p * 3);
    const float po1 = __builtin_nontemporal_load(pos2 + p * 3 + 1);
    const float po2 = __builtin_nontemporal_load(pos2 + p * 3 + 2);

    f16x8 A0 = *(const f16x8*)(x3f + (size_t)s * 32 + quad * 8);  // k 0..31
    if (quad == 0) {                                              // k 32..34
      A1[0] = (_Float16)(pos3[s * 3 + 0] - po0);
      A1[1] = (_Float16)(pos3[s * 3 + 1] - po1);
      A1[2] = (_Float16)(pos3[s * 3 + 2] - po2);
    }

    f32x4 d = {0.f, 0.f, 0.f, 0.f};
    d = mfma16(A0, Ba0, d);
    d = mfma16(A1, Ba1, d);
#pragma unroll
    for (int r = 0; r < 4; ++r)
      hw[(quad * 4 + r) * 24 + col] = (_Float16)celuf(d[r] + biasA);

    if (quad < 2) {  // k 0..15 valid: one b128 f16 read, no cvt
      P = *(const f16x8*)(hw + col * 24 + quad * 8);
    }
    f32x4 e = {0.f, 0.f, 0.f, 0.f};
    e = mfma16(P, Bb, e);

    float m0 = fmaxf(fmaxf(e[0], e[1]), fmaxf(e[2], e[3]));
    m0 = fmaxf(m0, __shfl_xor(m0, 16, 64));
    m0 = fmaxf(m0, __shfl_xor(m0, 32, 64));
    if (lane < 16)
      __builtin_nontemporal_store((_Float16)celuf(m0 + biasB),
                                  x2f + (size_t)p * 16 + col);
  }
}

// ---------------------------------------------------------------------------
// Level 1: PointConv (16 -> 8 -> 8) + final linear + log_sigmoid (round-4 loop).
// ---------------------------------------------------------------------------
__global__ __launch_bounds__(256) void l1_kernel(
    const _Float16* __restrict__ x2f, const float* __restrict__ pos2,
    const float* __restrict__ pos1, const int* __restrict__ src1,
    const float* __restrict__ w3a, const float* __restrict__ b3a,
    const float* __restrict__ w3b, const float* __restrict__ b3b,
    const float* __restrict__ wlin, const float* __restrict__ blin,
    float* __restrict__ out) {
  __shared__ _Float16 hbuf[4][16 * 8];  // 16 B rows
  const int lane = threadIdx.x & 63;
  const int wid = threadIdx.x >> 6;
  const int col = lane & 15;
  const int quad = lane >> 4;
  _Float16* hw = hbuf[wid];

  f16x8 Ba, Bb;
#pragma unroll
  for (int j = 0; j < 8; ++j) {
    int k = quad * 8 + j;
    Ba[j] = (k < 19 && col < 8) ? (_Float16)w3a[k * 8 + col] : (_Float16)0.f;
    Bb[j] = (k < 8 && col < 8) ? (_Float16)w3b[k * 8 + col] : (_Float16)0.f;
  }
  const float biasA = (col < 8) ? b3a[col] : 0.f;
  const float biasB = (col < 8) ? b3b[col] : 0.f;
  const float wl = (col < 8) ? wlin[col] : 0.f;
  const float bl = blin[0];

  const int gwave = blockIdx.x * 4 + wid;
  const int nw = gridDim.x * 4;

  f16x8 A = {};  // quad3 always zero; quad2 j3..7 zero
  f16x8 P = {};  // quad0 fully rewritten per point

  for (int p = gwave; p < N1C; p += nw) {
    const int s = __builtin_nontemporal_load(src1 + p * 16 + col);
    const float po0 = __builtin_nontemporal_load(pos1 + p * 3);
    const float po1 = __builtin_nontemporal_load(pos1 + p * 3 + 1);
    const float po2 = __builtin_nontemporal_load(pos1 + p * 3 + 2);

    // A[m=col=edge][k=quad*8+j]: quads 0,1 = feat 0..15; quad 2: rel k=16..18
    if (quad < 2) {
      A = *(const f16x8*)(x2f + (size_t)s * 16 + quad * 8);
    } else if (quad == 2) {
      A[0] = (_Float16)(pos2[s * 3 + 0] - po0);
      A[1] = (_Float16)(pos2[s * 3 + 1] - po1);
      A[2] = (_Float16)(pos2[s * 3 + 2] - po2);
    }
    f32x4 d = {0.f, 0.f, 0.f, 0.f};
    d = mfma16(A, Ba, d);

    if (col < 8) {
#pragma unroll
      for (int r = 0; r < 4; ++r)
        hw[(quad * 4 + r) * 8 + col] = (_Float16)celuf(d[r] + biasA);
    }
    if (quad == 0) {  // k = 0..7 valid: whole f16 row in one b128 read
      P = *(const f16x8*)(hw + col * 8);
    }
    f32x4 e = {0.f, 0.f, 0.f, 0.f};
    e = mfma16(P, Bb, e);

    float m0 = fmaxf(fmaxf(e[0], e[1]), fmaxf(e[2], e[3]));
    m0 = fmaxf(m0, __shfl_xor(m0, 16, 64));
    m0 = fmaxf(m0, __shfl_xor(m0, 32, 64));
    // lane0 needs sum over cols 0..7 (cols 8..15 contribute 0)
    float t = (col < 8) ? celuf(m0 + biasB) * wl : 0.f;
    t += __shfl_xor(t, 1, 64);
    t += __shfl_xor(t, 2, 64);
    t += __shfl_xor(t, 4, 64);
    if (lane == 0) __builtin_nontemporal_store(logsigf(t + bl), out + p);
  }
}

extern "C" void kernel_launch(void* const* d_in, const int* in_sizes, int n_in,
                              void* d_out, int out_size, void* d_ws, size_t ws_size,
                              hipStream_t stream) {
  const float* z_mask = (const float*)d_in[0];
  const float* pos4 = (const float*)d_in[1];
  const float* pos3 = (const float*)d_in[2];
  const float* pos2 = (const float*)d_in[3];
  const float* pos1 = (const float*)d_in[4];
  const float* w1a = (const float*)d_in[9];
  const float* b1a = (const float*)d_in[10];
  const float* w1b = (const float*)d_in[11];
  const float* b1b = (const float*)d_in[12];
  const float* w2a = (const float*)d_in[13];
  const float* b2a = (const float*)d_in[14];
  const float* w2b = (const float*)d_in[15];
  const float* b2b = (const float*)d_in[16];
  const float* w3a = (const float*)d_in[17];
  const float* b3a = (const float*)d_in[18];
  const float* w3b = (const float*)d_in[19];
  const float* b3b = (const float*)d_in[20];
  const float* wlin = (const float*)d_in[21];
  const float* blin = (const float*)d_in[22];
  const int* src3 = (const int*)d_in[23];
  const int* src2 = (const int*)d_in[25];
  const int* src1 = (const int*)d_in[27];

  // ws layout: [x3f 4 MB][regionB 4 MB]
  // regionB: zf (live prep..l3) then x2f (live l2..l1) — disjoint lifetimes.
  _Float16* x3f = (_Float16*)d_ws;                                 // [N3][32] f16
  _Float16* zf = (_Float16*)((char*)d_ws + (size_t)N3C * 32 * 2);  // [N4][64] f16
  _Float16* x2f = zf;                                              // [N2][16] f16
  float* out = (float*)d_out;

  zhalf_kernel<<<(N4C * 64) / (256 * 4), 256, 0, stream>>>(z_mask, zf);
  l3_kernel<<<4096, 256, 0, stream>>>(zf, pos4, pos3, src3, w1a, b1a, w1b, b1b, x3f);
  l2_kernel<<<16384, 256, 0, stream>>>(x3f, pos3, pos2, src2, w2a, b2a, w2b, b2b, x2f);
  l1_kernel<<<16384, 256, 0, stream>>>(x2f, pos2, pos1, src1, w3a, b3a, w3b, b3b,
                                       wlin, blin, out);
}

// Round 8
// 311.843 us; speedup vs baseline: 1.2473x; 1.2473x over previous
//
#include <hip/hip_runtime.h>
#include <math.h>

#define N4C 32768
#define N3C 65536
#define N2C 131072
#define N1C 262144

typedef _Float16 f16x8 __attribute__((ext_vector_type(8)));
typedef _Float16 f16x4 __attribute__((ext_vector_type(4)));
typedef float f32x4 __attribute__((ext_vector_type(4)));

__device__ __forceinline__ f32x4 mfma16(f16x8 a, f16x8 b, f32x4 c) {
  return __builtin_amdgcn_mfma_f32_16x16x32_f16(a, b, c, 0, 0, 0);
}

// fast celu: expm1(x) ~= __expf(x)-1 (v_exp_f32, abs err ~1e-7)
__device__ __forceinline__ float celuf(float x) {
  return x > 0.f ? x : (__expf(x) - 1.f);
}

// log_sigmoid(x) = min(x,0) - log(1 + exp(-|x|))
__device__ __forceinline__ float logsigf(float x) {
  float e = __expf(-fabsf(x));
  return fminf(x, 0.f) - __logf(1.f + e);
}

// ---------------------------------------------------------------------------
// Prep: z_mask [N4*64] f32 -> zf f16 (4 MB table; plain stores keep it L2-warm)
// ---------------------------------------------------------------------------
__global__ __launch_bounds__(256) void zhalf_kernel(const float* __restrict__ z,
                                                    _Float16* __restrict__ zf) {
  const int i = (blockIdx.x * 256 + threadIdx.x) * 4;
  float4 f = *(const float4*)(z + i);
  f16x4 h;
  h[0] = (_Float16)f.x; h[1] = (_Float16)f.y;
  h[2] = (_Float16)f.z; h[3] = (_Float16)f.w;
  *(f16x4*)(zf + i) = h;
}

// ---------------------------------------------------------------------------
// Level 3: PointConv (64 -> 64 -> 32), f16 MFMA, wave per point (16 edges = M).
// Round-4 structure (best measured). f16 LDS round-trip (0 bank conflicts).
// p-indexed pos reads via readfirstlane -> scalar loads.
// ---------------------------------------------------------------------------
__global__ __launch_bounds__(256) void l3_kernel(
    const _Float16* __restrict__ zf, const float* __restrict__ pos4,
    const float* __restrict__ pos3, const int* __restrict__ src3,
    const float* __restrict__ w1a, const float* __restrict__ b1a,
    const float* __restrict__ w1b, const float* __restrict__ b1b,
    _Float16* __restrict__ x3f) {
  __shared__ _Float16 hbuf[4][16 * 80];  // 160 B rows, 16B-aligned reads
  const int lane = threadIdx.x & 63;
  const int wid = threadIdx.x >> 6;
  const int col = lane & 15;   // MFMA n / A row m (edge)
  const int quad = lane >> 4;  // k-subchunk selector
  _Float16* hw = hbuf[wid];

  // B frags layer a: B[k][n], k = c*32 + quad*8 + j (K=67 pad 96), n = t*16+col
  f16x8 Ba[3][4];
#pragma unroll
  for (int c = 0; c < 3; ++c)
#pragma unroll
    for (int t = 0; t < 4; ++t)
#pragma unroll
      for (int j = 0; j < 8; ++j) {
        int k = c * 32 + quad * 8 + j;
        Ba[c][t][j] = (k < 67) ? (_Float16)w1a[k * 64 + t * 16 + col] : (_Float16)0.f;
      }
  f16x8 Bb[2][2];
#pragma unroll
  for (int c = 0; c < 2; ++c)
#pragma unroll
    for (int t = 0; t < 2; ++t)
#pragma unroll
      for (int j = 0; j < 8; ++j) {
        int k = c * 32 + quad * 8 + j;
        Bb[c][t][j] = (_Float16)w1b[k * 32 + t * 16 + col];
      }
  const float biasA0 = b1a[col], biasA1 = b1a[16 + col];
  const float biasA2 = b1a[32 + col], biasA3 = b1a[48 + col];
  const float biasB0 = b1b[col], biasB1 = b1b[16 + col];

  const int gwave = blockIdx.x * 4 + wid;
  const int nw = gridDim.x * 4;

  f16x8 A2 = {};  // only quad0 j0..2 rewritten per point; rest stay 0

  for (int p = gwave; p < N3C; p += nw) {
    const int s = src3[p * 16 + col];
    const int up = __builtin_amdgcn_readfirstlane(p);  // wave-uniform -> s_load
    const float po0 = pos3[up * 3 + 0];
    const float po1 = pos3[up * 3 + 1];
    const float po2 = pos3[up * 3 + 2];

    const _Float16* zr = zf + (size_t)s * 64;
    f16x8 A0 = *(const f16x8*)(zr + quad * 8);        // k 0..31
    f16x8 A1 = *(const f16x8*)(zr + 32 + quad * 8);   // k 32..63
    if (quad == 0) {                                  // k 64..66 = rel
      A2[0] = (_Float16)(pos4[s * 3 + 0] - po0);
      A2[1] = (_Float16)(pos4[s * 3 + 1] - po1);
      A2[2] = (_Float16)(pos4[s * 3 + 2] - po2);
    }

    f32x4 d[4];
#pragma unroll
    for (int t = 0; t < 4; ++t) {
      f32x4 acc = {0.f, 0.f, 0.f, 0.f};
      acc = mfma16(A0, Ba[0][t], acc);
      acc = mfma16(A1, Ba[1][t], acc);
      acc = mfma16(A2, Ba[2][t], acc);
      d[t] = acc;
    }
    // C layout: row = quad*4 + r, col = n. celu -> f16 LDS [16][80].
#pragma unroll
    for (int r = 0; r < 4; ++r) {
      _Float16* bp = hw + (quad * 4 + r) * 80 + col;
      bp[0]  = (_Float16)celuf(d[0][r] + biasA0);
      bp[16] = (_Float16)celuf(d[1][r] + biasA1);
      bp[32] = (_Float16)celuf(d[2][r] + biasA2);
      bp[48] = (_Float16)celuf(d[3][r] + biasA3);
    }
    // same-wave LDS, in-order: no barrier. A'[m=col][k=c*32+quad*8+j]
    f16x8 P0 = *(const f16x8*)(hw + col * 80 + quad * 8);
    f16x8 P1 = *(const f16x8*)(hw + col * 80 + 32 + quad * 8);
    f32x4 e[2];
#pragma unroll
    for (int t = 0; t < 2; ++t) {
      f32x4 acc = {0.f, 0.f, 0.f, 0.f};
      acc = mfma16(P0, Bb[0][t], acc);
      acc = mfma16(P1, Bb[1][t], acc);
      e[t] = acc;
    }
    float m0 = fmaxf(fmaxf(e[0][0], e[0][1]), fmaxf(e[0][2], e[0][3]));
    float m1 = fmaxf(fmaxf(e[1][0], e[1][1]), fmaxf(e[1][2], e[1][3]));
    m0 = fmaxf(m0, __shfl_xor(m0, 16, 64));
    m0 = fmaxf(m0, __shfl_xor(m0, 32, 64));
    m1 = fmaxf(m1, __shfl_xor(m1, 16, 64));
    m1 = fmaxf(m1, __shfl_xor(m1, 32, 64));
    if (lane < 16) {
      _Float16* row = x3f + (size_t)p * 32;
      row[col]      = (_Float16)celuf(m0 + biasB0);  // max(x)+b == max(x+b)
      row[16 + col] = (_Float16)celuf(m1 + biasB1);
    }
  }
}

// ---------------------------------------------------------------------------
// Level 2: PointConv (32 -> 16 -> 16), f16 MFMA wave-per-point (round-4 loop).
// ---------------------------------------------------------------------------
__global__ __launch_bounds__(256) void l2_kernel(
    const _Float16* __restrict__ x3f, const float* __restrict__ pos3,
    const float* __restrict__ pos2, const int* __restrict__ src2,
    const float* __restrict__ w2a, const float* __restrict__ b2a,
    const float* __restrict__ w2b, const float* __restrict__ b2b,
    _Float16* __restrict__ x2f) {
  __shared__ _Float16 hbuf[4][16 * 24];  // 48 B rows, 16B-aligned reads
  const int lane = threadIdx.x & 63;
  const int wid = threadIdx.x >> 6;
  const int col = lane & 15;
  const int quad = lane >> 4;
  _Float16* hw = hbuf[wid];

  f16x8 Ba0, Ba1, Bb;
#pragma unroll
  for (int j = 0; j < 8; ++j) {
    int k = quad * 8 + j;
    Ba0[j] = (_Float16)w2a[k * 16 + col];                       // k 0..31
    Ba1[j] = (k + 32 < 35) ? (_Float16)w2a[(k + 32) * 16 + col] // k 32..34
                           : (_Float16)0.f;
    Bb[j] = (k < 16) ? (_Float16)w2b[k * 16 + col] : (_Float16)0.f;
  }
  const float biasA = b2a[col];
  const float biasB = b2b[col];

  const int gwave = blockIdx.x * 4 + wid;
  const int nw = gridDim.x * 4;

  f16x8 A1 = {};  // quad0 j0..2 rewritten per point
  f16x8 P = {};   // quads 0,1 fully rewritten per point

  for (int p = gwave; p < N2C; p += nw) {
    const int s = src2[p * 16 + col];
    const int up = __builtin_amdgcn_readfirstlane(p);
    const float po0 = pos2[up * 3 + 0];
    const float po1 = pos2[up * 3 + 1];
    const float po2 = pos2[up * 3 + 2];

    f16x8 A0 = *(const f16x8*)(x3f + (size_t)s * 32 + quad * 8);  // k 0..31
    if (quad == 0) {                                              // k 32..34
      A1[0] = (_Float16)(pos3[s * 3 + 0] - po0);
      A1[1] = (_Float16)(pos3[s * 3 + 1] - po1);
      A1[2] = (_Float16)(pos3[s * 3 + 2] - po2);
    }

    f32x4 d = {0.f, 0.f, 0.f, 0.f};
    d = mfma16(A0, Ba0, d);
    d = mfma16(A1, Ba1, d);
#pragma unroll
    for (int r = 0; r < 4; ++r)
      hw[(quad * 4 + r) * 24 + col] = (_Float16)celuf(d[r] + biasA);

    if (quad < 2) {  // k 0..15 valid: one b128 f16 read, no cvt
      P = *(const f16x8*)(hw + col * 24 + quad * 8);
    }
    f32x4 e = {0.f, 0.f, 0.f, 0.f};
    e = mfma16(P, Bb, e);

    float m0 = fmaxf(fmaxf(e[0], e[1]), fmaxf(e[2], e[3]));
    m0 = fmaxf(m0, __shfl_xor(m0, 16, 64));
    m0 = fmaxf(m0, __shfl_xor(m0, 32, 64));
    if (lane < 16) x2f[(size_t)p * 16 + col] = (_Float16)celuf(m0 + biasB);
  }
}

// ---------------------------------------------------------------------------
// Level 1: PointConv (16 -> 8 -> 8) + final linear + log_sigmoid (round-4 loop).
// ---------------------------------------------------------------------------
__global__ __launch_bounds__(256) void l1_kernel(
    const _Float16* __restrict__ x2f, const float* __restrict__ pos2,
    const float* __restrict__ pos1, const int* __restrict__ src1,
    const float* __restrict__ w3a, const float* __restrict__ b3a,
    const float* __restrict__ w3b, const float* __restrict__ b3b,
    const float* __restrict__ wlin, const float* __restrict__ blin,
    float* __restrict__ out) {
  __shared__ _Float16 hbuf[4][16 * 8];  // 16 B rows
  const int lane = threadIdx.x & 63;
  const int wid = threadIdx.x >> 6;
  const int col = lane & 15;
  const int quad = lane >> 4;
  _Float16* hw = hbuf[wid];

  f16x8 Ba, Bb;
#pragma unroll
  for (int j = 0; j < 8; ++j) {
    int k = quad * 8 + j;
    Ba[j] = (k < 19 && col < 8) ? (_Float16)w3a[k * 8 + col] : (_Float16)0.f;
    Bb[j] = (k < 8 && col < 8) ? (_Float16)w3b[k * 8 + col] : (_Float16)0.f;
  }
  const float biasA = (col < 8) ? b3a[col] : 0.f;
  const float biasB = (col < 8) ? b3b[col] : 0.f;
  const float wl = (col < 8) ? wlin[col] : 0.f;
  const float bl = blin[0];

  const int gwave = blockIdx.x * 4 + wid;
  const int nw = gridDim.x * 4;

  f16x8 A = {};  // quad3 always zero; quad2 j3..7 zero
  f16x8 P = {};  // quad0 fully rewritten per point

  for (int p = gwave; p < N1C; p += nw) {
    const int s = src1[p * 16 + col];
    const int up = __builtin_amdgcn_readfirstlane(p);
    const float po0 = pos1[up * 3 + 0];
    const float po1 = pos1[up * 3 + 1];
    const float po2 = pos1[up * 3 + 2];

    // A[m=col=edge][k=quad*8+j]: quads 0,1 = feat 0..15; quad 2: rel k=16..18
    if (quad < 2) {
      A = *(const f16x8*)(x2f + (size_t)s * 16 + quad * 8);
    } else if (quad == 2) {
      A[0] = (_Float16)(pos2[s * 3 + 0] - po0);
      A[1] = (_Float16)(pos2[s * 3 + 1] - po1);
      A[2] = (_Float16)(pos2[s * 3 + 2] - po2);
    }
    f32x4 d = {0.f, 0.f, 0.f, 0.f};
    d = mfma16(A, Ba, d);

    if (col < 8) {
#pragma unroll
      for (int r = 0; r < 4; ++r)
        hw[(quad * 4 + r) * 8 + col] = (_Float16)celuf(d[r] + biasA);
    }
    if (quad == 0) {  // k = 0..7 valid: whole f16 row in one b128 read
      P = *(const f16x8*)(hw + col * 8);
    }
    f32x4 e = {0.f, 0.f, 0.f, 0.f};
    e = mfma16(P, Bb, e);

    float m0 = fmaxf(fmaxf(e[0], e[1]), fmaxf(e[2], e[3]));
    m0 = fmaxf(m0, __shfl_xor(m0, 16, 64));
    m0 = fmaxf(m0, __shfl_xor(m0, 32, 64));
    // lane0 needs sum over cols 0..7 (cols 8..15 contribute 0): 3 shuffles
    float t = (col < 8) ? celuf(m0 + biasB) * wl : 0.f;
    t += __shfl_xor(t, 1, 64);
    t += __shfl_xor(t, 2, 64);
    t += __shfl_xor(t, 4, 64);
    if (lane == 0) out[p] = logsigf(t + bl);
  }
}

extern "C" void kernel_launch(void* const* d_in, const int* in_sizes, int n_in,
                              void* d_out, int out_size, void* d_ws, size_t ws_size,
                              hipStream_t stream) {
  const float* z_mask = (const float*)d_in[0];
  const float* pos4 = (const float*)d_in[1];
  const float* pos3 = (const float*)d_in[2];
  const float* pos2 = (const float*)d_in[3];
  const float* pos1 = (const float*)d_in[4];
  const float* w1a = (const float*)d_in[9];
  const float* b1a = (const float*)d_in[10];
  const float* w1b = (const float*)d_in[11];
  const float* b1b = (const float*)d_in[12];
  const float* w2a = (const float*)d_in[13];
  const float* b2a = (const float*)d_in[14];
  const float* w2b = (const float*)d_in[15];
  const float* b2b = (const float*)d_in[16];
  const float* w3a = (const float*)d_in[17];
  const float* b3a = (const float*)d_in[18];
  const float* w3b = (const float*)d_in[19];
  const float* b3b = (const float*)d_in[20];
  const float* wlin = (const float*)d_in[21];
  const float* blin = (const float*)d_in[22];
  const int* src3 = (const int*)d_in[23];
  const int* src2 = (const int*)d_in[25];
  const int* src1 = (const int*)d_in[27];

  // ws layout: [x3f 4 MB][regionB 4 MB]
  // regionB: zf (live prep..l3) then x2f (live l2..l1) — disjoint lifetimes.
  _Float16* x3f = (_Float16*)d_ws;                                 // [N3][32] f16
  _Float16* zf = (_Float16*)((char*)d_ws + (size_t)N3C * 32 * 2);  // [N4][64] f16
  _Float16* x2f = zf;                                              // [N2][16] f16
  float* out = (float*)d_out;

  zhalf_kernel<<<(N4C * 64) / (256 * 4), 256, 0, stream>>>(z_mask, zf);
  l3_kernel<<<2048, 256, 0, stream>>>(zf, pos4, pos3, src3, w1a, b1a, w1b, b1b, x3f);
  l2_kernel<<<8192, 256, 0, stream>>>(x3f, pos3, pos2, src2, w2a, b2a, w2b, b2b, x2f);
  l1_kernel<<<8192, 256, 0, stream>>>(x2f, pos2, pos1, src1, w3a, b3a, w3b, b3b,
                                      wlin, blin, out);
}